// Round 2
// baseline (544.864 us; speedup 1.0000x reference)
//
#include <hip/hip_runtime.h>
#include <hip/hip_bf16.h>
#include <hip/hip_fp16.h>

#define NN 131072
#define KK 27
#define CC 32
#define EPSV 1e-5f

// ---------------------------------------------------------------------------
// Tier-1 (gather) workspace layout:
//   [0,256)        f32 stats
//   [256,+512K)    u32 cnt[N]            (bucket sizes, memset 0)
//   [WS_WPERM]     f16 permuted weights  (55296 B)
//   [WS_PAIRS]     u32 pairs[N][64]      (packed (i<<5)|k, no memset needed)
//   [WS_DATA16]    f16 data[N][32]
#define WS_STATS   0
#define WS_CNT     256
#define WS_WPERM   (256 + 524288)
#define WS_PAIRS   579840
#define WS_DATA16  34134272
#define WS_NEED_GATHER ((size_t)WS_DATA16 + (size_t)NN * CC * 2)

// Tier-2 (R1 atomic-scatter) layout: stats 0, bf16 wperm 256, f16 acc 65536
#define T2_WPERM 256
#define T2_ACC   65536
#define WS_NEED_T2 ((size_t)T2_ACC + (size_t)NN * CC * 2)

#define CAP  64      // bucket capacity (Poisson(27): P(>64) ~ 5e-9/row)
#define XSTR 472     // LDS X row stride in halves (14*32=448 used, pad for banks)

typedef __bf16 bf16x8 __attribute__((ext_vector_type(8)));
typedef _Float16 f16x8 __attribute__((ext_vector_type(8)));
typedef short s16x8 __attribute__((ext_vector_type(8)));
typedef float f32x4 __attribute__((ext_vector_type(4)));

__device__ inline unsigned short f2bf(float f) {
    unsigned int u = __float_as_uint(f);
    u += 0x7FFF + ((u >> 16) & 1);   // round-to-nearest-even
    return (unsigned short)(u >> 16);
}
__device__ inline unsigned short f2h(float f) {
    return __builtin_bit_cast(unsigned short, __float2half(f));
}
__device__ inline unsigned int h2add(unsigned int a, unsigned int b) {
    __half2 x = __builtin_bit_cast(__half2, a);
    __half2 y = __builtin_bit_cast(__half2, b);
    return __builtin_bit_cast(unsigned int, __hadd2(x, y));
}

// ===========================================================================
// Tier-1 kernels
// ===========================================================================

// Fused prep: blocks [0,2048) convert data f32->f16 (8 elems/thread);
// blocks [2048,2156) permute weights into f16 MFMA B-fragment layout.
// Layout (verified in the running scatter kernel): logical out-channel c is
// computed by MFMA ch-half (c&1) at physical column (c>>1); fragment element
// (fl, j): fl = col | ((ci>>3)<<4), j = ci&7.
__global__ __launch_bounds__(256) void prep_kernel(
    const float* __restrict__ data, const float* __restrict__ weight,
    unsigned short* __restrict__ data16, unsigned short* __restrict__ wperm)
{
    const int b = blockIdx.x;
    if (b < 2048) {
        const int tg = b * 256 + threadIdx.x;          // 8 floats each
        const float4 v0 = ((const float4*)data)[tg * 2];
        const float4 v1 = ((const float4*)data)[tg * 2 + 1];
        union { unsigned short us[8]; uint4 u4; } o;
        o.us[0] = f2h(v0.x); o.us[1] = f2h(v0.y);
        o.us[2] = f2h(v0.z); o.us[3] = f2h(v0.w);
        o.us[4] = f2h(v1.x); o.us[5] = f2h(v1.y);
        o.us[6] = f2h(v1.z); o.us[7] = f2h(v1.w);
        ((uint4*)data16)[tg] = o.u4;
    } else {
        const int p = (b - 2048) * 256 + threadIdx.x;  // < 27648 exactly
        const int k  = p >> 10;
        const int ci = (p >> 5) & 31;
        const int c  = p & 31;
        const unsigned short v = f2h(weight[p]);
        const int chalf = c & 1;
        const int col   = c >> 1;
        const int fl = col | ((ci >> 3) << 4);
        const int j = ci & 7;
        wperm[(((k << 1) | chalf) * 64 + fl) * 8 + j] = v;
    }
}

// Build inverse buckets: for each (i,k) pair, append (i<<5)|k to bucket of
// its destination o = neigh[i][k]. 3.5M 4B returning atomics (14 MB) instead
// of 226 MB of payload atomics in the scatter formulation.
__global__ __launch_bounds__(256) void fill_kernel(
    const int* __restrict__ neigh, unsigned int* __restrict__ cnt,
    unsigned int* __restrict__ pairs)
{
    const unsigned int p = blockIdx.x * 256 + threadIdx.x;   // grid exact N*27
    const unsigned int o = (unsigned int)neigh[p];
    const unsigned int i = p / 27u;
    const unsigned int k = p - i * 27u;
    const unsigned int slot = atomicAdd(&cnt[o], 1u);
    if (slot < CAP) pairs[(o << 6) | slot] = (i << 5) | k;
}

// Gather-GEMM: block = 4 waves, each wave owns 16 output rows.
// Per tap-group g (taps [14g, 14g+NT)):
//   fill:  X[16][NT*32] (f16, LDS) += gathered data rows (per-row serial walk,
//          4 lanes/row, pair prefetch depth 4 / data depth 2 -> no dependent
//          global-latency stall per step)
//   mfma:  acc += X @ Wflat  (B-fragments from L2-hot wperm, prefetched)
// Output rows written once (f32, non-atomic); BN stats fused (64 atomics/blk).
__global__ __launch_bounds__(256) void gather_kernel(
    const unsigned short* __restrict__ data16,
    const unsigned short* __restrict__ wperm,
    const unsigned int* __restrict__ cnt, const unsigned int* __restrict__ pairs,
    float* __restrict__ out, float* __restrict__ stats)
{
    __shared__ unsigned short Xs[4][16 * XSTR];   // 60416 B
    __shared__ float sarr[4][16][4];              // 1024 B

    const int tid = threadIdx.x;
    const int lane = tid & 63;
    const int wv = tid >> 6;
    const int row0 = blockIdx.x * 64 + wv * 16;

    // fill roles: 16 rows x 4 lanes; lane seg covers 16 B of the 64 B data row
    const int rl  = lane >> 2;
    const int seg = lane & 3;
    const int row_g = row0 + rl;

    const unsigned int cfull = cnt[row_g];
    const int c = (int)(cfull < (unsigned)CAP ? cfull : (unsigned)CAP);
    const int cm1 = c > 0 ? c - 1 : 0;
    int maxc = c;
    #pragma unroll
    for (int off = 1; off < 64; off <<= 1) {
        const int o2 = __shfl_xor(maxc, off);
        maxc = maxc > o2 ? maxc : o2;
    }

    const unsigned int* prow = pairs + ((size_t)row_g << 6);

    // MFMA roles
    const int quad = lane >> 4;
    const int m = lane & 15;
    f32x4 acc0 = {0.f, 0.f, 0.f, 0.f}, acc1 = {0.f, 0.f, 0.f, 0.f};
    const uint4* wq = (const uint4*)wperm;
    const uint4* dq = (const uint4*)data16;
    unsigned short* xw = &Xs[wv][0];

    for (int g = 0; g < 2; ++g) {
        const int k0 = g * 14;
        const int NT = g ? 13 : 14;

        // zero this wave's X tile (16*XSTR/8 = 944 uint4)
        {
            const uint4 z = {0u, 0u, 0u, 0u};
            #pragma unroll
            for (int it = 0; it < 15; ++it) {
                const int idx = lane + it * 64;
                if (idx < (16 * XSTR) / 8) ((uint4*)xw)[idx] = z;
            }
        }

        // ---- pipelined bucket walk ----
        unsigned int p0 = prow[0];
        unsigned int p1 = prow[1 < cm1 ? 1 : cm1];
        unsigned int p2 = prow[2 < cm1 ? 2 : cm1];
        unsigned int p3 = prow[3 < cm1 ? 3 : cm1];
        uint4 d0 = {0,0,0,0}, d1 = {0,0,0,0};
        {
            const int kk = (int)(p0 & 31u) - k0;
            if (kk >= 0 && kk < NT) d0 = dq[(((p0 >> 5) & (NN - 1)) << 2) | seg];
        }
        {
            const int kk = (int)(p1 & 31u) - k0;
            if (kk >= 0 && kk < NT) d1 = dq[(((p1 >> 5) & (NN - 1)) << 2) | seg];
        }

        for (int t = 0; t < maxc; ++t) {
            const int tp = t + 4;
            const unsigned int pn = prow[tp < cm1 ? tp : cm1];
            // issue data for t+2 (p2 fetched 2 iters ago)
            uint4 dn = {0,0,0,0};
            {
                const int kk = (int)(p2 & 31u) - k0;
                if (kk >= 0 && kk < NT) dn = dq[(((p2 >> 5) & (NN - 1)) << 2) | seg];
            }
            // consume pair t (d0 issued 2 iters ago)
            {
                const int kk = (int)(p0 & 31u) - k0;
                if (t < c && kk >= 0 && kk < NT) {
                    uint4* xp = (uint4*)(xw + rl * XSTR + kk * 32 + seg * 8);
                    uint4 cur = *xp;
                    cur.x = h2add(cur.x, d0.x); cur.y = h2add(cur.y, d0.y);
                    cur.z = h2add(cur.z, d0.z); cur.w = h2add(cur.w, d0.w);
                    *xp = cur;
                }
            }
            p0 = p1; p1 = p2; p2 = p3; p3 = pn;
            d0 = d1; d1 = dn;
        }

        // ---- MFMA over this group's taps (B prefetched from L2-hot wperm) ----
        uint4 b0 = wq[(k0 * 2 + 0) * 64 + lane];
        uint4 b1 = wq[(k0 * 2 + 1) * 64 + lane];
        for (int kk = 0; kk < NT; ++kk) {
            const int ktn = (kk + 1 < NT) ? (k0 + kk + 1) : (k0 + kk);
            const uint4 nb0 = wq[(ktn * 2 + 0) * 64 + lane];
            const uint4 nb1 = wq[(ktn * 2 + 1) * 64 + lane];
            const uint4 av = *(const uint4*)(xw + m * XSTR + kk * 32 + quad * 8);
            const f16x8 af = __builtin_bit_cast(f16x8, av);
            acc0 = __builtin_amdgcn_mfma_f32_16x16x32_f16(
                af, __builtin_bit_cast(f16x8, b0), acc0, 0, 0, 0);
            acc1 = __builtin_amdgcn_mfma_f32_16x16x32_f16(
                af, __builtin_bit_cast(f16x8, b1), acc1, 0, 0, 0);
            b0 = nb0; b1 = nb1;
        }
    }

    // ---- write pre-BN rows (once, non-atomic) + fused stats ----
    float s0 = 0.f, s1 = 0.f, q0 = 0.f, q1 = 0.f;
    #pragma unroll
    for (int r = 0; r < 4; ++r) {
        const float a = acc0[r], b = acc1[r];
        s0 += a; s1 += b; q0 += a * a; q1 += b * b;
        float2 v; v.x = a; v.y = b;   // logical channels 2m, 2m+1
        *(float2*)(out + ((size_t)(row0 + quad * 4 + r)) * 32 + 2 * m) = v;
    }
    s0 += __shfl_xor(s0, 16); s0 += __shfl_xor(s0, 32);
    s1 += __shfl_xor(s1, 16); s1 += __shfl_xor(s1, 32);
    q0 += __shfl_xor(q0, 16); q0 += __shfl_xor(q0, 32);
    q1 += __shfl_xor(q1, 16); q1 += __shfl_xor(q1, 32);
    if (quad == 0) {
        sarr[wv][m][0] = s0; sarr[wv][m][1] = s1;
        sarr[wv][m][2] = q0; sarr[wv][m][3] = q1;
    }
    __syncthreads();
    if (tid < 64) {
        const int ch = tid & 31, isq = tid >> 5;
        float v = 0.f;
        #pragma unroll
        for (int w = 0; w < 4; ++w) v += sarr[w][ch >> 1][(isq << 1) | (ch & 1)];
        atomicAdd(&stats[isq * 32 + ch], v);
    }
}

// ===========================================================================
// Tier-2: R1 atomic-scatter path (unchanged, proven at 271 us)
// ===========================================================================
__global__ __launch_bounds__(256) void prep_weights_bf16_kernel(
    const float* __restrict__ weight, unsigned short* __restrict__ wperm)
{
    const int p = blockIdx.x * 256 + threadIdx.x;
    if (p >= KK * 1024) return;
    const int k  = p >> 10;
    const int ci = (p >> 5) & 31;
    const int c  = p & 31;
    const unsigned short v = f2bf(weight[p]);
    const int chalf = c & 1;
    const int col   = c >> 1;
    const int fl = col | ((ci >> 3) << 4);
    const int j = ci & 7;
    wperm[(((k << 1) | chalf) * 64 + fl) * 8 + j] = v;
}

__global__ __launch_bounds__(256) void scatter_kernel(
    const float* __restrict__ data, const unsigned short* __restrict__ wperm,
    const int* __restrict__ neigh, __half2* __restrict__ acc2)
{
    const int tid = threadIdx.x;
    const int lane = tid & 63;
    const int wv = tid >> 6;
    const int node_base = blockIdx.x * 128 + wv * 32;
    const int quad = lane >> 4;
    const int m = lane & 15;
    const int rq = quad << 2;

    s16x8 afr[2];
    #pragma unroll
    for (int g = 0; g < 2; ++g) {
        const int node = node_base + g * 16 + m;
        const float* src = data + node * 32 + quad * 8;
        const float4 v0 = *(const float4*)(src);
        const float4 v1 = *(const float4*)(src + 4);
        s16x8 s;
        s[0] = (short)f2bf(v0.x); s[1] = (short)f2bf(v0.y);
        s[2] = (short)f2bf(v0.z); s[3] = (short)f2bf(v0.w);
        s[4] = (short)f2bf(v1.x); s[5] = (short)f2bf(v1.y);
        s[6] = (short)f2bf(v1.z); s[7] = (short)f2bf(v1.w);
        afr[g] = s;
    }

    const s16x8* wp = (const s16x8*)wperm;
    const f32x4 zero = {0.f, 0.f, 0.f, 0.f};

    int nj0[4], nj1[4];
    #pragma unroll
    for (int r = 0; r < 4; ++r) {
        nj0[r] = neigh[(node_base + rq + r) * KK];
        nj1[r] = neigh[(node_base + 16 + rq + r) * KK];
    }
    s16x8 bs0 = wp[lane];
    s16x8 bs1 = wp[64 + lane];

    for (int k = 0; k < KK; ++k) {
        const int kn = (k < KK - 1) ? k + 1 : k;
        int nn0[4], nn1[4];
        #pragma unroll
        for (int r = 0; r < 4; ++r) {
            nn0[r] = neigh[(node_base + rq + r) * KK + kn];
            nn1[r] = neigh[(node_base + 16 + rq + r) * KK + kn];
        }
        const s16x8 nbs0 = wp[(kn * 2) * 64 + lane];
        const s16x8 nbs1 = wp[(kn * 2 + 1) * 64 + lane];
        {
            const f32x4 d0 = __builtin_amdgcn_mfma_f32_16x16x32_bf16(
                __builtin_bit_cast(bf16x8, afr[0]), __builtin_bit_cast(bf16x8, bs0),
                zero, 0, 0, 0);
            const f32x4 d1 = __builtin_amdgcn_mfma_f32_16x16x32_bf16(
                __builtin_bit_cast(bf16x8, afr[0]), __builtin_bit_cast(bf16x8, bs1),
                zero, 0, 0, 0);
            #pragma unroll
            for (int r = 0; r < 4; ++r) {
                __half2 v;
                v.x = __float2half(d0[r]);
                v.y = __float2half(d1[r]);
                unsafeAtomicAdd(&acc2[nj0[r] * 16 + m], v);
            }
        }
        {
            const f32x4 d0 = __builtin_amdgcn_mfma_f32_16x16x32_bf16(
                __builtin_bit_cast(bf16x8, afr[1]), __builtin_bit_cast(bf16x8, bs0),
                zero, 0, 0, 0);
            const f32x4 d1 = __builtin_amdgcn_mfma_f32_16x16x32_bf16(
                __builtin_bit_cast(bf16x8, afr[1]), __builtin_bit_cast(bf16x8, bs1),
                zero, 0, 0, 0);
            #pragma unroll
            for (int r = 0; r < 4; ++r) {
                __half2 v;
                v.x = __float2half(d0[r]);
                v.y = __float2half(d1[r]);
                unsafeAtomicAdd(&acc2[nj1[r] * 16 + m], v);
            }
        }
        bs0 = nbs0; bs1 = nbs1;
        #pragma unroll
        for (int r = 0; r < 4; ++r) { nj0[r] = nn0[r]; nj1[r] = nn1[r]; }
    }
}

__global__ __launch_bounds__(256) void stats_kernel(
    const __half2* __restrict__ acc2, float* __restrict__ stats)
{
    __shared__ float ls[16][33], ls2[16][33];
    const int tid = threadIdx.x;
    const int c2 = tid & 15, rg = tid >> 4;
    float sx = 0.f, sy = 0.f, s2x = 0.f, s2y = 0.f;
    const int row0 = blockIdx.x * 512;
    for (int it = 0; it < 32; ++it) {
        const __half2 h = acc2[(row0 + it * 16 + rg) * 16 + c2];
        const float vx = __half2float(h.x), vy = __half2float(h.y);
        sx += vx; sy += vy; s2x += vx * vx; s2y += vy * vy;
    }
    ls[rg][2 * c2] = sx;  ls[rg][2 * c2 + 1] = sy;
    ls2[rg][2 * c2] = s2x; ls2[rg][2 * c2 + 1] = s2y;
    __syncthreads();
    if (tid < 32) {
        float S = 0.f, S2 = 0.f;
        #pragma unroll
        for (int g = 0; g < 16; ++g) { S += ls[g][tid]; S2 += ls2[g][tid]; }
        atomicAdd(&stats[tid], S);
        atomicAdd(&stats[32 + tid], S2);
    }
}

__global__ __launch_bounds__(256) void bn_relu_kernel(
    const __half2* __restrict__ acc2, float* __restrict__ out,
    const float* __restrict__ stats,
    const float* __restrict__ gamma, const float* __restrict__ beta)
{
    __shared__ float sc[32], sh[32];
    const int tid = threadIdx.x;
    if (tid < 32) {
        const float mean = stats[tid] * (1.0f / NN);
        const float var  = stats[32 + tid] * (1.0f / NN) - mean * mean;
        const float s = gamma[tid] * rsqrtf(var + EPSV);
        sc[tid] = s;
        sh[tid] = beta[tid] - mean * s;
    }
    __syncthreads();
    const int idx = blockIdx.x * 256 + tid;
    const int c0 = (idx & 3) << 3;
    const __half2 h4[4] = { acc2[idx * 4], acc2[idx * 4 + 1],
                            acc2[idx * 4 + 2], acc2[idx * 4 + 3] };
    float4 o0, o1;
    o0.x = fmaxf(__half2float(h4[0].x) * sc[c0]     + sh[c0],     0.f);
    o0.y = fmaxf(__half2float(h4[0].y) * sc[c0 + 1] + sh[c0 + 1], 0.f);
    o0.z = fmaxf(__half2float(h4[1].x) * sc[c0 + 2] + sh[c0 + 2], 0.f);
    o0.w = fmaxf(__half2float(h4[1].y) * sc[c0 + 3] + sh[c0 + 3], 0.f);
    o1.x = fmaxf(__half2float(h4[2].x) * sc[c0 + 4] + sh[c0 + 4], 0.f);
    o1.y = fmaxf(__half2float(h4[2].y) * sc[c0 + 5] + sh[c0 + 5], 0.f);
    o1.z = fmaxf(__half2float(h4[3].x) * sc[c0 + 6] + sh[c0 + 6], 0.f);
    o1.w = fmaxf(__half2float(h4[3].y) * sc[c0 + 7] + sh[c0 + 7], 0.f);
    ((float4*)out)[idx * 2]     = o0;
    ((float4*)out)[idx * 2 + 1] = o1;
}

// ===========================================================================
// Tier-3 fallback (f32 atomics into d_out) + shared BN-apply kernel
// ===========================================================================
__global__ __launch_bounds__(256) void scatter_f32_kernel(
    const float* __restrict__ data, const float* __restrict__ weight,
    const int* __restrict__ neigh, float* __restrict__ out)
{
    __shared__ unsigned short wfrag[KK * 2 * 64 * 8];
    const int tid = threadIdx.x;
    const int lane = tid & 63;
    const int wv = tid >> 6;
    const int node_base = blockIdx.x * 128;
    for (int p = tid; p < KK * 1024; p += 256) {
        const int k  = p >> 10;
        const int ci = (p >> 5) & 31;
        const int c  = p & 31;
        const unsigned short v = f2bf(weight[p]);
        const int chalf = c >> 4;
        const int fl = (c & 15) | ((ci >> 3) << 4);
        const int j = ci & 7;
        wfrag[(((k << 1) | chalf) * 64 + fl) * 8 + j] = v;
    }
    const int quad = lane >> 4;
    const int m = lane & 15;
    s16x8 afr[2];
    #pragma unroll
    for (int g = 0; g < 2; ++g) {
        const int node = node_base + wv * 32 + g * 16 + m;
        const float* src = data + node * 32 + quad * 8;
        const float4 v0 = *(const float4*)(src);
        const float4 v1 = *(const float4*)(src + 4);
        s16x8 s;
        s[0] = (short)f2bf(v0.x); s[1] = (short)f2bf(v0.y);
        s[2] = (short)f2bf(v0.z); s[3] = (short)f2bf(v0.w);
        s[4] = (short)f2bf(v1.x); s[5] = (short)f2bf(v1.y);
        s[6] = (short)f2bf(v1.z); s[7] = (short)f2bf(v1.w);
        afr[g] = s;
    }
    __syncthreads();
    const int rq = quad << 2;
    const f32x4 zero = {0.f, 0.f, 0.f, 0.f};
    for (int k = 0; k < KK; ++k) {
        int nj[2][4];
        #pragma unroll
        for (int g = 0; g < 2; ++g)
            #pragma unroll
            for (int r = 0; r < 4; ++r) {
                const int node = node_base + wv * 32 + g * 16 + rq + r;
                nj[g][r] = neigh[node * KK + k];
            }
        #pragma unroll
        for (int ch = 0; ch < 2; ++ch) {
            const s16x8 bs = *(const s16x8*)&wfrag[((((k << 1) | ch)) * 64 + lane) * 8];
            const bf16x8 bfr = __builtin_bit_cast(bf16x8, bs);
            const int c = (ch << 4) | m;
            #pragma unroll
            for (int g = 0; g < 2; ++g) {
                f32x4 a2 = __builtin_amdgcn_mfma_f32_16x16x32_bf16(
                    __builtin_bit_cast(bf16x8, afr[g]), bfr, zero, 0, 0, 0);
                #pragma unroll
                for (int r = 0; r < 4; ++r)
                    __hip_atomic_fetch_add(&out[nj[g][r] * 32 + c], a2[r],
                                           __ATOMIC_RELAXED, __HIP_MEMORY_SCOPE_AGENT);
            }
        }
    }
}

__global__ __launch_bounds__(256) void stats_f32_kernel(
    const float* __restrict__ out, float* __restrict__ stats)
{
    __shared__ float ls[256], ls2[256];
    const int tid = threadIdx.x;
    const int c = tid & 31, rg = tid >> 5;
    float s = 0.f, s2 = 0.f;
    const int row0 = blockIdx.x * 512;
    for (int it = 0; it < 64; ++it) {
        const float v = out[(row0 + it * 8 + rg) * 32 + c];
        s += v; s2 += v * v;
    }
    ls[tid] = s; ls2[tid] = s2;
    __syncthreads();
    if (tid < 32) {
        float S = 0.f, S2 = 0.f;
        #pragma unroll
        for (int r = 0; r < 8; ++r) { S += ls[r * 32 + tid]; S2 += ls2[r * 32 + tid]; }
        atomicAdd(&stats[tid], S);
        atomicAdd(&stats[32 + tid], S2);
    }
}

// BN+ReLU in place on f32 out (used by tier-1 and tier-3)
__global__ __launch_bounds__(256) void bn_relu_f32_kernel(
    float* __restrict__ out, const float* __restrict__ stats,
    const float* __restrict__ gamma, const float* __restrict__ beta)
{
    __shared__ float sc[32], sh[32];
    const int tid = threadIdx.x;
    if (tid < 32) {
        const float mean = stats[tid] * (1.0f / NN);
        const float var  = stats[32 + tid] * (1.0f / NN) - mean * mean;
        const float s = gamma[tid] * rsqrtf(var + EPSV);
        sc[tid] = s;
        sh[tid] = beta[tid] - mean * s;
    }
    __syncthreads();
    const int idx = blockIdx.x * 256 + tid;
    float4 v = ((float4*)out)[idx];
    const int cb = (idx & 7) << 2;
    v.x = fmaxf(v.x * sc[cb]     + sh[cb],     0.f);
    v.y = fmaxf(v.y * sc[cb + 1] + sh[cb + 1], 0.f);
    v.z = fmaxf(v.z * sc[cb + 2] + sh[cb + 2], 0.f);
    v.w = fmaxf(v.w * sc[cb + 3] + sh[cb + 3], 0.f);
    ((float4*)out)[idx] = v;
}

// ===========================================================================
extern "C" void kernel_launch(void* const* d_in, const int* in_sizes, int n_in,
                              void* d_out, int out_size, void* d_ws, size_t ws_size,
                              hipStream_t stream) {
    const float* data   = (const float*)d_in[0];
    const float* weight = (const float*)d_in[1];
    const float* gamma  = (const float*)d_in[2];
    const float* beta   = (const float*)d_in[3];
    const int*   neigh  = (const int*)d_in[4];
    float* out = (float*)d_out;
    char* ws = (char*)d_ws;
    float* stats = (float*)(ws + WS_STATS);

    if (ws_size >= WS_NEED_GATHER) {
        unsigned int*   cnt    = (unsigned int*)(ws + WS_CNT);
        unsigned short* wperm  = (unsigned short*)(ws + WS_WPERM);
        unsigned int*   pairs  = (unsigned int*)(ws + WS_PAIRS);
        unsigned short* data16 = (unsigned short*)(ws + WS_DATA16);
        // zero stats + cnt in one shot (contiguous)
        hipMemsetAsync(ws, 0, 256 + (size_t)NN * 4, stream);
        prep_kernel<<<2156, 256, 0, stream>>>(data, weight, data16, wperm);
        fill_kernel<<<(NN * KK) / 256, 256, 0, stream>>>(neigh, cnt, pairs);
        gather_kernel<<<NN / 64, 256, 0, stream>>>(data16, wperm, cnt, pairs, out, stats);
        bn_relu_f32_kernel<<<(NN * CC / 4) / 256, 256, 0, stream>>>(out, stats, gamma, beta);
    } else if (ws_size >= WS_NEED_T2) {
        __half2* acc2 = (__half2*)(ws + T2_ACC);
        unsigned short* wperm = (unsigned short*)(ws + T2_WPERM);
        hipMemsetAsync(ws + WS_STATS, 0, 256, stream);
        hipMemsetAsync(ws + T2_ACC, 0, (size_t)NN * CC * 2, stream);
        prep_weights_bf16_kernel<<<(KK * 1024 + 255) / 256, 256, 0, stream>>>(weight, wperm);
        scatter_kernel<<<NN / 128, 256, 0, stream>>>(data, wperm, neigh, acc2);
        stats_kernel<<<NN / 512, 256, 0, stream>>>(acc2, stats);
        bn_relu_kernel<<<(NN * CC / 8) / 256, 256, 0, stream>>>(acc2, out, stats, gamma, beta);
    } else {
        hipMemsetAsync(out, 0, (size_t)NN * CC * sizeof(float), stream);
        hipMemsetAsync(ws + WS_STATS, 0, 64 * sizeof(float), stream);
        scatter_f32_kernel<<<NN / 128, 256, 0, stream>>>(data, weight, neigh, out);
        stats_f32_kernel<<<NN / 512, 256, 0, stream>>>(out, stats);
        bn_relu_f32_kernel<<<(NN * CC / 4) / 256, 256, 0, stream>>>(out, stats, gamma, beta);
    }
}